// Round 1
// baseline (31287.125 us; speedup 1.0000x reference)
//
#include <hip/hip_runtime.h>
#include <cmath>

// DHT: out[n,c,a,r] = sum over pixels (x,y) of feat[n,c,y,x] where
//   r = clip(rint((x-128)*cos(a*pi/180) + (y-128)*sin(a*pi/180)) + 361, 0, 722)
// Shapes: feat[4,128,256,256] f32 -> out[4,128,180,723] f32.

#define NA 180
#define NR 723
#define HW 65536      // 256*256
#define NC 512        // 4*128
#define CHUNK 8       // angles per LDS accumulation chunk

// ---------------------------------------------------------------------------
// Kernel A: exact bin table, int16, [180][65536].
// Rows 0..45 and 135..179 (phase-1 angles, |cos|>=0.707): entry j maps to
//   (x = j&255, y = j>>8)   (row-major pixel order; lanes sweep x)
// Rows 46..134 (phase-2 angles, |sin|>=0.707): entry j maps to
//   (x = j>>8, y = j&255)   (transposed; lanes sweep y)
// fp64 with explicit non-fused mul/add + rint to bit-match numpy round().
// ---------------------------------------------------------------------------
__global__ __launch_bounds__(1024) void dht_table(short* __restrict__ tab) {
    const int a = blockIdx.y;
    const int j = blockIdx.x * 1024 + threadIdx.x;
    int x, y;
    const bool transposed = (a >= 46 && a <= 134);
    if (transposed) { x = j >> 8; y = j & 255; }
    else            { x = j & 255; y = j >> 8; }
    const double theta = (double)a * (M_PI / 180.0);
    const double c = cos(theta);
    const double s = sin(theta);
    const double xc = (double)(x - 128);
    const double yc = (double)(y - 128);
    const double rho = __dadd_rn(__dmul_rn(xc, c), __dmul_rn(yc, s));
    int r = (int)rint(rho) + 361;   // rint = round-half-even, matches np.round
    r = min(max(r, 0), NR - 1);
    tab[(size_t)a * HW + j] = (short)r;
}

// ---------------------------------------------------------------------------
// Kernel B: one block per (n,c) image. 1024 threads hold the full image in
// registers (64 px/thread). Two phases so the 64 lanes of each wave always
// spread across the fast-bin axis (|coef| >= 0.707 -> at most ~2 lanes/bin).
// LDS accumulators for CHUNK angles at a time; exclusive output ownership ->
// plain stores, no global atomics.
// ---------------------------------------------------------------------------
__global__ __launch_bounds__(1024, 4) void dht_main(const float* __restrict__ feat,
                                                    const short* __restrict__ tab,
                                                    float* __restrict__ out) {
    __shared__ float acc[CHUNK * NR];
    const int t = threadIdx.x;
    const int nc = blockIdx.x;
    const int lanelo = t & 255;    // x in phase 1, y in phase 2
    const int g = t >> 8;          // 0..3: segment along the scan axis
    const float* __restrict__ fbase = feat + (size_t)nc * HW;
    float* __restrict__ obase = out + (size_t)nc * (NA * NR);

    for (int i = t; i < CHUNK * NR; i += 1024) acc[i] = 0.f;

    float px[64];

    // ---------------- phase 1: angles {0..45} U {135..179} (91 angles) ------
    // thread holds column x=lanelo, rows y = 64g..64g+63  (coalesced loads)
    #pragma unroll
    for (int k = 0; k < 64; ++k)
        px[k] = fbase[((g * 64 + k) << 8) | lanelo];
    __syncthreads();

    for (int cb = 0; cb < 91; cb += CHUNK) {
        const int cn = min(CHUNK, 91 - cb);
        for (int al = 0; al < cn; ++al) {
            const int ai = cb + al;
            const int a = (ai <= 45) ? ai : ai + 89;   // 46.. -> 135..
            const short* __restrict__ trow = tab + (size_t)a * HW;
            float* __restrict__ arow = acc + al * NR;
            #pragma unroll
            for (int k = 0; k < 64; ++k) {
                const int idx = trow[((g * 64 + k) << 8) | lanelo];
                atomicAdd(&arow[idx], px[k]);
            }
        }
        __syncthreads();
        for (int i = t; i < cn * NR; i += 1024) {
            const int al = i / NR;
            const int r  = i - al * NR;
            const int ai = cb + al;
            const int a = (ai <= 45) ? ai : ai + 89;
            obase[(size_t)a * NR + r] = acc[i];
            acc[i] = 0.f;
        }
        __syncthreads();
    }

    // ---------------- phase 2: angles 46..134 (89 angles) -------------------
    // thread holds row y=lanelo, cols x = 64g..64g+63 (reload; L1 absorbs the
    // per-instruction stride, each 64B line fully consumed by one lane)
    #pragma unroll
    for (int k = 0; k < 64; ++k)
        px[k] = fbase[(lanelo << 8) | (g * 64 + k)];

    for (int cb = 0; cb < 89; cb += CHUNK) {
        const int cn = min(CHUNK, 89 - cb);
        for (int al = 0; al < cn; ++al) {
            const int a = 46 + cb + al;
            const short* __restrict__ trow = tab + (size_t)a * HW;
            float* __restrict__ arow = acc + al * NR;
            #pragma unroll
            for (int k = 0; k < 64; ++k) {
                // transposed table rows: entry j=(64g+k)*256+lanelo is pixel
                // (x=64g+k, y=lanelo) -> matches px[k]; loads stay coalesced
                const int idx = trow[((g * 64 + k) << 8) | lanelo];
                atomicAdd(&arow[idx], px[k]);
            }
        }
        __syncthreads();
        for (int i = t; i < cn * NR; i += 1024) {
            const int al = i / NR;
            const int r  = i - al * NR;
            const int a = 46 + cb + al;
            obase[(size_t)a * NR + r] = acc[i];
            acc[i] = 0.f;
        }
        __syncthreads();
    }
}

extern "C" void kernel_launch(void* const* d_in, const int* in_sizes, int n_in,
                              void* d_out, int out_size, void* d_ws, size_t ws_size,
                              hipStream_t stream) {
    const float* feat = (const float*)d_in[0];
    float* out = (float*)d_out;
    short* tab = (short*)d_ws;

    const size_t tab_bytes = (size_t)NA * HW * sizeof(short);   // ~23.6 MB
    if (ws_size < tab_bytes) return;   // fail loud via validation, don't fault

    dim3 gA(HW / 1024, NA);
    hipLaunchKernelGGL(dht_table, gA, dim3(1024), 0, stream, tab);

    hipLaunchKernelGGL(dht_main, dim3(NC), dim3(1024), 0, stream,
                       feat, tab, out);
}

// Round 2
// 30825.974 us; speedup vs baseline: 1.0150x; 1.0150x over previous
//
#include <hip/hip_runtime.h>
#include <cmath>

// DHT: out[n,c,a,r] = sum over pixels (x,y) of feat[n,c,y,x] where
//   r = clip(rint((x-128)*cos(a*pi/180) + (y-128)*sin(a*pi/180)) + 361, 0, 722)
// feat[4,128,256,256] f32 -> out[4,128,180,723] f32.

#define NA 180
#define NR 723
#define HW 65536      // 256*256
#define NC 512        // 4*128
#define CHUNK 16      // angles per LDS accumulation chunk (16*723*4 = 46.3 KB)
#define GRP 8         // pixels per thread per group (register tile; NO spill)
#define NGRP 8        // 64 px/thread total, in 8 groups

// ---------------------------------------------------------------------------
// Kernel A: exact bin table, int16, [180][65536].
// Rows 0..45 & 135..179 (phase-1, |cos|>=0.707): entry j -> (x=j&255, y=j>>8)
// Rows 46..134          (phase-2, |sin|>=0.707): entry j -> (x=j>>8, y=j&255)
// fp64 non-fused mul/add + rint bit-matches numpy round(). (R1: absmax 0.25,
// pure f32 sum-order noise -> table is exact.)
// ---------------------------------------------------------------------------
__global__ __launch_bounds__(1024) void dht_table(short* __restrict__ tab) {
    const int a = blockIdx.y;
    const int j = blockIdx.x * 1024 + threadIdx.x;
    int x, y;
    if (a >= 46 && a <= 134) { x = j >> 8; y = j & 255; }
    else                     { x = j & 255; y = j >> 8; }
    const double theta = (double)a * (M_PI / 180.0);
    const double c = cos(theta);
    const double s = sin(theta);
    const double rho = __dadd_rn(__dmul_rn((double)(x - 128), c),
                                 __dmul_rn((double)(y - 128), s));
    int r = (int)rint(rho) + 361;
    r = min(max(r, 0), NR - 1);
    tab[(size_t)a * HW + j] = (short)r;
}

// ---------------------------------------------------------------------------
// Kernel B: one block per (n,c) image, 1024 threads. Two phases keep each
// wave's 64 lanes spread along the fast-bin axis (>=0.707 bin step -> <=2
// lanes per LDS bin). Per angle-chunk of 16: zero LDS acc, sweep the image in
// 8 register-groups of 8 px/thread (no big register array -> no scratch
// spill, the R1 killer), LDS ds_add_f32 atomics, then coalesced flush.
// ---------------------------------------------------------------------------
__global__ __launch_bounds__(1024, 8) void dht_main(const float* __restrict__ feat,
                                                    const short* __restrict__ tab,
                                                    float* __restrict__ out) {
    __shared__ float acc[CHUNK * NR];
    const int t = threadIdx.x;
    const int nc = blockIdx.x;
    const int lanelo = t & 255;    // x in phase 1, y in phase 2
    const int g = t >> 8;          // 0..3: segment along the scan axis
    const float* __restrict__ fbase = feat + (size_t)nc * HW;
    float* __restrict__ obase = out + (size_t)nc * (NA * NR);

    for (int phase = 0; phase < 2; ++phase) {
        const int nAng = phase ? 89 : 91;
        for (int cb = 0; cb < nAng; cb += CHUNK) {
            const int cn = min(CHUNK, nAng - cb);
            for (int i = t; i < cn * NR; i += 1024) acc[i] = 0.f;
            __syncthreads();

            for (int grp = 0; grp < NGRP; ++grp) {
                const int k0 = g * 64 + grp * GRP;   // offset along scan axis
                float px[GRP];
                if (phase == 0) {
                    // column x=lanelo, rows y=k0..k0+7: coalesced across lanes
                    #pragma unroll
                    for (int k = 0; k < GRP; ++k)
                        px[k] = fbase[((k0 + k) << 8) | lanelo];
                } else {
                    // row y=lanelo, cols x=k0..k0+7: contiguous -> float4 x2
                    const float4* p = (const float4*)(fbase + (lanelo << 8) + k0);
                    const float4 v0 = p[0], v1 = p[1];
                    px[0] = v0.x; px[1] = v0.y; px[2] = v0.z; px[3] = v0.w;
                    px[4] = v1.x; px[5] = v1.y; px[6] = v1.z; px[7] = v1.w;
                }

                for (int al = 0; al < cn; ++al) {
                    const int ai = cb + al;
                    const int a = phase ? (46 + ai) : (ai <= 45 ? ai : ai + 89);
                    const short* __restrict__ trow = tab + (size_t)a * HW;
                    float* __restrict__ arow = acc + al * NR;
                    #pragma unroll
                    for (int k = 0; k < GRP; ++k) {
                        const int idx = trow[((k0 + k) << 8) | lanelo];
                        atomicAdd(&arow[idx], px[k]);
                    }
                }
            }
            __syncthreads();

            for (int i = t; i < cn * NR; i += 1024) {
                const int al = i / NR;
                const int r  = i - al * NR;
                const int ai = cb + al;
                const int a = phase ? (46 + ai) : (ai <= 45 ? ai : ai + 89);
                obase[(size_t)a * NR + r] = acc[i];
            }
            __syncthreads();
        }
    }
}

extern "C" void kernel_launch(void* const* d_in, const int* in_sizes, int n_in,
                              void* d_out, int out_size, void* d_ws, size_t ws_size,
                              hipStream_t stream) {
    const float* feat = (const float*)d_in[0];
    float* out = (float*)d_out;
    short* tab = (short*)d_ws;

    const size_t tab_bytes = (size_t)NA * HW * sizeof(short);   // ~23.6 MB
    if (ws_size < tab_bytes) return;

    dim3 gA(HW / 1024, NA);
    hipLaunchKernelGGL(dht_table, gA, dim3(1024), 0, stream, tab);
    hipLaunchKernelGGL(dht_main, dim3(NC), dim3(1024), 0, stream, feat, tab, out);
}

// Round 3
// 30789.783 us; speedup vs baseline: 1.0162x; 1.0012x over previous
//
#include <hip/hip_runtime.h>
#include <cmath>

// DHT: out[n,c,a,r] = sum over pixels (x,y) of feat[n,c,y,x] where
//   r = clip(rint((x-128)*cos(a*pi/180) + (y-128)*sin(a*pi/180)) + 361, 0, 722)
// feat[4,128,256,256] f32 -> out[4,128,180,723] f32.
//
// R1: spill-bound (64px/thread in "registers" -> scratch), 31.3 ms.
// R2: spill fixed (VGPR 20, traffic clean) -> STILL 30.8 ms. Bottleneck is
//     atomicAdd(float*) on LDS compiling to a CAS retry loop (~200 cyc/visit,
//     VALUBusy 0.87% matches the CAS arithmetic). This round: the ONLY change
//     is atomicAdd -> unsafeAtomicAdd (native ds_add_f32, fire-and-forget).

#define NA 180
#define NR 723
#define HW 65536      // 256*256
#define NC 512        // 4*128
#define CHUNK 16      // angles per LDS accumulation chunk (16*723*4 = 46.3 KB)
#define GRP 8         // pixels per thread per group (register tile; no spill)
#define NGRP 8        // 64 px/thread total, in 8 groups

// ---------------------------------------------------------------------------
// Kernel A: exact bin table, int16, [180][65536].
// Rows 0..45 & 135..179 (phase-1, |cos|>=0.707): entry j -> (x=j&255, y=j>>8)
// Rows 46..134          (phase-2, |sin|>=0.707): entry j -> (x=j>>8, y=j&255)
// fp64 non-fused mul/add + rint bit-matches numpy round(). (R1/R2: absmax
// 0.25 = f32 sum-order noise only -> table is exact.)
// ---------------------------------------------------------------------------
__global__ __launch_bounds__(1024) void dht_table(short* __restrict__ tab) {
    const int a = blockIdx.y;
    const int j = blockIdx.x * 1024 + threadIdx.x;
    int x, y;
    if (a >= 46 && a <= 134) { x = j >> 8; y = j & 255; }
    else                     { x = j & 255; y = j >> 8; }
    const double theta = (double)a * (M_PI / 180.0);
    const double c = cos(theta);
    const double s = sin(theta);
    const double rho = __dadd_rn(__dmul_rn((double)(x - 128), c),
                                 __dmul_rn((double)(y - 128), s));
    int r = (int)rint(rho) + 361;
    r = min(max(r, 0), NR - 1);
    tab[(size_t)a * HW + j] = (short)r;
}

// ---------------------------------------------------------------------------
// Kernel B: one block per (n,c) image, 1024 threads. Two phases keep each
// wave's 64 lanes spread along the fast-bin axis (|coef|>=0.707 -> <=2 lanes
// per bin). Per 16-angle chunk: zero LDS acc, sweep image in 8 register
// groups of 8 px/thread, native ds_add_f32 atomics, coalesced flush.
// ---------------------------------------------------------------------------
__global__ __launch_bounds__(1024, 8) void dht_main(const float* __restrict__ feat,
                                                    const short* __restrict__ tab,
                                                    float* __restrict__ out) {
    __shared__ float acc[CHUNK * NR];
    const int t = threadIdx.x;
    const int nc = blockIdx.x;
    const int lanelo = t & 255;    // x in phase 1, y in phase 2
    const int g = t >> 8;          // 0..3: segment along the scan axis
    const float* __restrict__ fbase = feat + (size_t)nc * HW;
    float* __restrict__ obase = out + (size_t)nc * (NA * NR);

    for (int phase = 0; phase < 2; ++phase) {
        const int nAng = phase ? 89 : 91;
        for (int cb = 0; cb < nAng; cb += CHUNK) {
            const int cn = min(CHUNK, nAng - cb);
            for (int i = t; i < cn * NR; i += 1024) acc[i] = 0.f;
            __syncthreads();

            for (int grp = 0; grp < NGRP; ++grp) {
                const int k0 = g * 64 + grp * GRP;   // offset along scan axis
                float px[GRP];
                if (phase == 0) {
                    // column x=lanelo, rows y=k0..k0+7: coalesced across lanes
                    #pragma unroll
                    for (int k = 0; k < GRP; ++k)
                        px[k] = fbase[((k0 + k) << 8) | lanelo];
                } else {
                    // row y=lanelo, cols x=k0..k0+7: contiguous -> float4 x2
                    const float4* p = (const float4*)(fbase + (lanelo << 8) + k0);
                    const float4 v0 = p[0], v1 = p[1];
                    px[0] = v0.x; px[1] = v0.y; px[2] = v0.z; px[3] = v0.w;
                    px[4] = v1.x; px[5] = v1.y; px[6] = v1.z; px[7] = v1.w;
                }

                for (int al = 0; al < cn; ++al) {
                    const int ai = cb + al;
                    const int a = phase ? (46 + ai) : (ai <= 45 ? ai : ai + 89);
                    const short* __restrict__ trow = tab + (size_t)a * HW;
                    float* __restrict__ arow = acc + al * NR;
                    #pragma unroll
                    for (int k = 0; k < GRP; ++k) {
                        const int idx = trow[((k0 + k) << 8) | lanelo];
                        // native ds_add_f32 (no CAS loop). Denormal-flush
                        // semantics are irrelevant for this data/tolerance.
                        unsafeAtomicAdd(&arow[idx], px[k]);
                    }
                }
            }
            __syncthreads();

            for (int i = t; i < cn * NR; i += 1024) {
                const int al = i / NR;
                const int r  = i - al * NR;
                const int ai = cb + al;
                const int a = phase ? (46 + ai) : (ai <= 45 ? ai : ai + 89);
                obase[(size_t)a * NR + r] = acc[i];
            }
            __syncthreads();
        }
    }
}

extern "C" void kernel_launch(void* const* d_in, const int* in_sizes, int n_in,
                              void* d_out, int out_size, void* d_ws, size_t ws_size,
                              hipStream_t stream) {
    const float* feat = (const float*)d_in[0];
    float* out = (float*)d_out;
    short* tab = (short*)d_ws;

    const size_t tab_bytes = (size_t)NA * HW * sizeof(short);   // ~23.6 MB
    if (ws_size < tab_bytes) return;

    dim3 gA(HW / 1024, NA);
    hipLaunchKernelGGL(dht_table, gA, dim3(1024), 0, stream, tab);
    hipLaunchKernelGGL(dht_main, dim3(NC), dim3(1024), 0, stream, feat, tab, out);
}

// Round 4
// 30767.676 us; speedup vs baseline: 1.0169x; 1.0007x over previous
//
#include <hip/hip_runtime.h>
#include <cmath>

// DHT: out[n,c,a,r] = sum over pixels (x,y) of feat[n,c,y,x],
//   r = clip(rint((x-128)*cos(a deg) + (y-128)*sin(a deg)) + 361, 0, 722)
// feat[4,128,256,256] f32 -> out[4,128,180,723] f32.
//
// R1 31.3ms (spill) / R2 30.8ms (clean) / R3 30.8ms (unsafeAtomicAdd):
// identical times across different codegen -> bottleneck is the per-visit
// GLOBAL bin-table load (6e9 x 2B, latency-serialized; VGPR=20 confirms no
// load batching), not the LDS atomic (already native ds_add_f32).
// R4: compress table to base+increment-bitmask (along the scan axis
// |delta rho| <= 0.7071 -> bin steps are 0/±1 monotone). One u32 per
// (angle, lane, 8-px window): bits[0:16]=start bin, bits[16:23]=increments.
// Per visit: ~3 VALU + ds_add_f32, ZERO global loads.

#define NA 180
#define NR 723
#define HW 65536      // 256*256
#define NC 512        // 4*128
#define CHUNK 16      // angles per LDS accumulation chunk (16*723*4 = 46.3 KB)
#define GRP 8         // pixels per thread per window
#define NWIN 32       // windows per scan line (256/8)

// phase-1 angles: a in [0,45] U [135,179]  (|cos|>=0.707; lanes sweep x, scan y)
// phase-2 angles: a in [46,134]            (|sin|>=0.707; lanes sweep y, scan x)
__device__ __forceinline__ bool is_phase2(int a) { return a >= 46 && a <= 134; }

// ---------------------------------------------------------------------------
// Kernel A: compressed exact bin table win[a][w][lane], u32.
//   lane = fast axis (x in ph1, y in ph2), w = 8-px window along scan axis.
//   base = r at k=w*8; bit (16+i) = |r(w*8+i) - r(w*8+i-1)| for i=1..7.
// Steps are exact 0/±1 (|coef| <= sin(45) < 1), sign is uniform per angle
// (+1 except ph2 with a>90). fp64 non-fused mul/add + rint bit-matches
// np.round (validated R1-R3: absmax 0.25 = f32 sum-order noise only).
// ---------------------------------------------------------------------------
__global__ __launch_bounds__(256) void dht_win(unsigned int* __restrict__ win) {
    const int lane = threadIdx.x;        // 0..255
    const int w = blockIdx.x;            // 0..31
    const int a = blockIdx.y;            // 0..179
    const double theta = (double)a * (M_PI / 180.0);
    const double c = cos(theta), s = sin(theta);
    const bool p2 = is_phase2(a);

    int prev = 0;
    unsigned int word = 0;
    #pragma unroll
    for (int i = 0; i < GRP; ++i) {
        const int k = w * GRP + i;
        const int x = p2 ? k : lane;
        const int y = p2 ? lane : k;
        const double rho = __dadd_rn(__dmul_rn((double)(x - 128), c),
                                     __dmul_rn((double)(y - 128), s));
        int r = (int)rint(rho) + 361;
        r = min(max(r, 0), NR - 1);
        if (i == 0) word = (unsigned int)r;
        else if (r != prev) word |= (1u << (15 + i));
        prev = r;
    }
    win[((size_t)a * NWIN + w) * 256 + lane] = word;
}

// ---------------------------------------------------------------------------
// Kernel B: one block per (n,c) image, 1024 threads (256 lanes x 4 scan
// segments). Per 16-angle chunk: zero LDS acc; sweep image in 8 windows of
// 8 px/thread (px held in regs across all 16 angles); per (angle, window)
// ONE u32 win-word load (L1/L2-hot, 64KB/chunk working set); walk bins by
// adding mask bits; ds_add_f32 into LDS; coalesced flush.
// ---------------------------------------------------------------------------
__global__ __launch_bounds__(1024, 8) void dht_main(const float* __restrict__ feat,
                                                    const unsigned int* __restrict__ win,
                                                    float* __restrict__ out) {
    __shared__ float acc[CHUNK * NR];
    const int t = threadIdx.x;
    const int nc = blockIdx.x;
    const int lanelo = t & 255;    // x in phase 1, y in phase 2
    const int g = t >> 8;          // 0..3: segment along the scan axis
    const float* __restrict__ fbase = feat + (size_t)nc * HW;
    float* __restrict__ obase = out + (size_t)nc * (NA * NR);

    for (int phase = 0; phase < 2; ++phase) {
        const int nAng = phase ? 89 : 91;
        for (int cb = 0; cb < nAng; cb += CHUNK) {
            const int cn = min(CHUNK, nAng - cb);
            for (int i = t; i < cn * NR; i += 1024) acc[i] = 0.f;
            __syncthreads();

            for (int grp = 0; grp < GRP; ++grp) {
                const int w = g * 8 + grp;           // window index, 0..31
                const int k0 = w * GRP;              // offset along scan axis
                float px[GRP];
                if (phase == 0) {
                    // column x=lanelo, rows y=k0..k0+7 (coalesced across lanes)
                    #pragma unroll
                    for (int k = 0; k < GRP; ++k)
                        px[k] = fbase[((k0 + k) << 8) | lanelo];
                } else {
                    // row y=lanelo, cols x=k0..k0+7 (contiguous -> float4 x2)
                    const float4* p = (const float4*)(fbase + (lanelo << 8) + k0);
                    const float4 v0 = p[0], v1 = p[1];
                    px[0] = v0.x; px[1] = v0.y; px[2] = v0.z; px[3] = v0.w;
                    px[4] = v1.x; px[5] = v1.y; px[6] = v1.z; px[7] = v1.w;
                }

                for (int al = 0; al < cn; ++al) {
                    const int ai = cb + al;
                    const int a = phase ? (46 + ai) : (ai <= 45 ? ai : ai + 89);
                    const int sgn = (phase && a > 90) ? -1 : 1;  // wave-uniform
                    const unsigned int wrd =
                        win[((size_t)a * NWIN + w) * 256 + lanelo];
                    float* __restrict__ arow = acc + al * NR;
                    int r = (int)(wrd & 0xffffu);
                    unsafeAtomicAdd(&arow[r], px[0]);
                    #pragma unroll
                    for (int k = 1; k < GRP; ++k) {
                        const int step = (int)((wrd >> (15 + k)) & 1u);
                        r += sgn > 0 ? step : -step;
                        unsafeAtomicAdd(&arow[r], px[k]);
                    }
                }
            }
            __syncthreads();

            for (int i = t; i < cn * NR; i += 1024) {
                const int al = i / NR;
                const int rr = i - al * NR;
                const int ai = cb + al;
                const int a = phase ? (46 + ai) : (ai <= 45 ? ai : ai + 89);
                obase[(size_t)a * NR + rr] = acc[i];
            }
            __syncthreads();
        }
    }
}

extern "C" void kernel_launch(void* const* d_in, const int* in_sizes, int n_in,
                              void* d_out, int out_size, void* d_ws, size_t ws_size,
                              hipStream_t stream) {
    const float* feat = (const float*)d_in[0];
    float* out = (float*)d_out;
    unsigned int* win = (unsigned int*)d_ws;

    const size_t win_bytes = (size_t)NA * NWIN * 256 * sizeof(unsigned int); // 5.9MB
    if (ws_size < win_bytes) return;

    hipLaunchKernelGGL(dht_win, dim3(NWIN, NA), dim3(256), 0, stream, win);
    hipLaunchKernelGGL(dht_main, dim3(NC), dim3(1024), 0, stream, feat, win, out);
}

// Round 5
// 2616.356 us; speedup vs baseline: 11.9583x; 11.7597x over previous
//
#include <hip/hip_runtime.h>
#include <cmath>

// DHT: out[n,c,a,r] = sum over px (x,y) of feat[n,c,y,x],
//   r = rint((x-128)*cos(a deg) + (y-128)*sin(a deg)) + 361   (always in [180,542])
// feat[4,128,256,256] f32 -> out[4,128,180,723] f32.
//
// R1-R4 all ~31ms across wildly different codegen -> invariant = the LDS
// atomic stream (6.04e9 ds_add_f32; measured ~3.1 cyc/LANE-atomic).
// R5: NO atomics. Per-wave private rows + 4-column lane segments walked
// column-major => concurrent lanes' bins differ by >=2 (4*|coef|>=2.83)
// => plain ds_read/add/ds_write RMW is race-free (same-wave DS ops are
// program-ordered; rows are wave-private; flush sums the 16 copies).

#define NA 180
#define NR 723
#define HW 65536
#define NC 512
#define CH 2          // angles per chunk
#define ROW_W 368     // bins span [180,542]; store r-176 in [4,366]
#define RBASE 176
#define NWIN 32       // 8-px windows along the scan axis

__device__ __forceinline__ bool is_phase2(int a) { return a >= 46 && a <= 134; }

// ---------------------------------------------------------------------------
// Kernel A (unchanged from R4, exactness validated): win[a][w][lane] u32 =
// base bin (bits 0..15) at scan=8w, step bits 16..22 for scan=8w+1..8w+7.
// Phase-1 rows (a in [0,45]u[135,179]): lane=x, scan=y. Phase-2: lane=y, scan=x.
// fp64 non-fused mul/add + rint bit-matches np.round.
// ---------------------------------------------------------------------------
__global__ __launch_bounds__(256) void dht_win(unsigned int* __restrict__ win) {
    const int lane = threadIdx.x;
    const int w = blockIdx.x;
    const int a = blockIdx.y;
    const double theta = (double)a * (M_PI / 180.0);
    const double c = cos(theta), s = sin(theta);
    const bool p2 = is_phase2(a);
    int prev = 0;
    unsigned int word = 0;
    #pragma unroll
    for (int i = 0; i < 8; ++i) {
        const int k = w * 8 + i;
        const int x = p2 ? k : lane;
        const int y = p2 ? lane : k;
        const double rho = __dadd_rn(__dmul_rn((double)(x - 128), c),
                                     __dmul_rn((double)(y - 128), s));
        int r = (int)rint(rho) + 361;
        r = min(max(r, 0), NR - 1);
        if (i == 0) word = (unsigned int)r;
        else if (r != prev) word |= (1u << (15 + i));
        prev = r;
    }
    win[((size_t)a * NWIN + w) * 256 + lane] = word;
}

// ---------------------------------------------------------------------------
// Kernel B: block = 1024 thr = 16 waves, one (n,c) image. Wave wv owns scan
// range [16wv,16wv+16); lane l owns fast-axis columns 4l..4l+3 (walked j-major
// so concurrent lanes are 4 columns apart -> distinct bins at every instant).
// Private rows[wave][CH][ROW_W]; register run-merge along scan; plain DS RMW.
// ---------------------------------------------------------------------------
__global__ __launch_bounds__(1024, 4) void dht_main(const float* __restrict__ feat,
                                                    const unsigned int* __restrict__ win,
                                                    float* __restrict__ out) {
    __shared__ float rows[16 * CH * ROW_W];   // 47.1 KB
    const int t = threadIdx.x;
    const int wv = t >> 6;
    const int l = t & 63;
    const int nc = blockIdx.x;
    const float* __restrict__ fbase = feat + (size_t)nc * HW;
    float* __restrict__ obase = out + (size_t)nc * (NA * NR);

    for (int phase = 0; phase < 2; ++phase) {
        const int nAng = phase ? 89 : 91;
        for (int cb = 0; cb < nAng; cb += CH) {
            const int cn = min(CH, nAng - cb);
            for (int i = t; i < 16 * CH * ROW_W; i += 1024) rows[i] = 0.f;
            __syncthreads();

            // ---- load this thread's 16(scan) x 4(col) px patch ----
            float px[16][4];
            if (phase == 0) {
                // rows y=16wv+k, cols x=4l..4l+3: one float4, fully coalesced
                #pragma unroll
                for (int k = 0; k < 16; ++k) {
                    const float4 q = *(const float4*)(fbase + ((16 * wv + k) << 8) + 4 * l);
                    px[k][0] = q.x; px[k][1] = q.y; px[k][2] = q.z; px[k][3] = q.w;
                }
            } else {
                // rows y=4l+j, cols x=16wv+4k4..+3: float4 along scan axis
                #pragma unroll
                for (int j = 0; j < 4; ++j)
                    #pragma unroll
                    for (int k4 = 0; k4 < 4; ++k4) {
                        const float4 q = *(const float4*)(fbase + ((4 * l + j) << 8) + 16 * wv + 4 * k4);
                        px[4 * k4 + 0][j] = q.x; px[4 * k4 + 1][j] = q.y;
                        px[4 * k4 + 2][j] = q.z; px[4 * k4 + 3][j] = q.w;
                    }
            }

            for (int ai = 0; ai < cn; ++ai) {
                const int aidx = cb + ai;
                const int a = phase ? (46 + aidx) : (aidx <= 45 ? aidx : aidx + 89);
                const int sgn = (phase && a > 90) ? -1 : 1;
                float* __restrict__ rp = rows + (wv * CH + ai) * ROW_W;

                #pragma unroll
                for (int w2 = 0; w2 < 2; ++w2) {
                    const int w = 2 * wv + w2;
                    const uint4 wq = *(const uint4*)(win + ((size_t)a * NWIN + w) * 256 + 4 * l);
                    #pragma unroll
                    for (int j = 0; j < 4; ++j) {
                        const unsigned int wrd = (&wq.x)[j];
                        int bin = (int)(wrd & 0xffffu) - RBASE;
                        float cur = px[8 * w2][j];
                        #pragma unroll
                        for (int k = 1; k < 8; ++k) {
                            if ((wrd >> (15 + k)) & 1u) {
                                rp[bin] += cur;          // plain DS RMW (race-free)
                                bin += sgn;
                                cur = px[8 * w2 + k][j];
                            } else {
                                cur += px[8 * w2 + k][j];
                            }
                        }
                        rp[bin] += cur;                  // window-end flush
                    }
                }
            }
            __syncthreads();

            // ---- flush: sum the 16 wave copies, write out (full 723 incl. zeros) ----
            for (int i = t; i < cn * NR; i += 1024) {
                const int al = i / NR;
                const int r = i - al * NR;
                const int aidx = cb + al;
                const int a = phase ? (46 + aidx) : (aidx <= 45 ? aidx : aidx + 89);
                float sum = 0.f;
                const int rl = r - RBASE;
                if (rl >= 0 && rl < ROW_W) {
                    #pragma unroll
                    for (int wv2 = 0; wv2 < 16; ++wv2)
                        sum += rows[(wv2 * CH + al) * ROW_W + rl];
                }
                obase[(size_t)a * NR + r] = sum;
            }
            __syncthreads();
        }
    }
}

extern "C" void kernel_launch(void* const* d_in, const int* in_sizes, int n_in,
                              void* d_out, int out_size, void* d_ws, size_t ws_size,
                              hipStream_t stream) {
    const float* feat = (const float*)d_in[0];
    float* out = (float*)d_out;
    unsigned int* win = (unsigned int*)d_ws;

    const size_t win_bytes = (size_t)NA * NWIN * 256 * sizeof(unsigned int); // 5.9MB
    if (ws_size < win_bytes) return;

    hipLaunchKernelGGL(dht_win, dim3(NWIN, NA), dim3(256), 0, stream, win);
    hipLaunchKernelGGL(dht_main, dim3(NC), dim3(1024), 0, stream, feat, win, out);
}